// Round 8
// baseline (315.391 us; speedup 1.0000x reference)
//
#include <hip/hip_runtime.h>

#define D 128
#define TILE_R 32
#define LDS_STRIDE 260
#define GBM 64            // rows (nodes) per fused-layer block
#define APAD 264          // 256 bf16 + 8 pad

#define NB 512            // coarse buckets
#define NPB 256           // nodes per bucket (dst >> 8)
#define EPB_A 2048        // edges per block in stage A

typedef __attribute__((ext_vector_type(8))) short bf16x8;
typedef __attribute__((ext_vector_type(4))) float f32x4;

static __device__ __forceinline__ ushort f2b(float f) {
    union { float f; uint u; } v; v.f = f;
    uint r = (v.u + 0x7FFFu + ((v.u >> 16) & 1u)) >> 16;   // RNE
    return (ushort)r;
}
static __device__ __forceinline__ float blo(uint u) {
    union { uint u; float f; } v; v.u = u << 16; return v.f;
}
static __device__ __forceinline__ float bhi(uint u) {
    union { uint u; float f; } v; v.u = u & 0xFFFF0000u; return v.f;
}

// ================= prep: conv(x->bf16) + Wt1 + Wt2 + bucket_count, one kernel =================
__global__ __launch_bounds__(256) void prep_kernel(
    const float* __restrict__ x, ushort* __restrict__ xb, int n8,
    const float* __restrict__ W1rel, const float* __restrict__ W1root, ushort* __restrict__ Wt1,
    const float* __restrict__ W2rel, const float* __restrict__ W2root, ushort* __restrict__ Wt2,
    const int* __restrict__ dst, int* __restrict__ bcnt, int nedges,
    int nConvBlocks, int nCountBlocks)
{
    __shared__ int h[NB];
    const int b = blockIdx.x, t = threadIdx.x;

    if (b < nConvBlocks) {
        int i = b * 256 + t;
        if (i >= n8) return;
        float4 a = reinterpret_cast<const float4*>(x)[i * 2];
        float4 c = reinterpret_cast<const float4*>(x)[i * 2 + 1];
        uint4 r;
        r.x = f2b(a.x) | ((uint)f2b(a.y) << 16);
        r.y = f2b(a.z) | ((uint)f2b(a.w) << 16);
        r.z = f2b(c.x) | ((uint)f2b(c.y) << 16);
        r.w = f2b(c.z) | ((uint)f2b(c.w) << 16);
        reinterpret_cast<uint4*>(xb)[i] = r;
    } else if (b < nConvBlocks + 256) {
        int wb = b - nConvBlocks;          // 0..255 ; 0..127 -> Wt1, 128..255 -> Wt2
        const float* Wrel  = (wb < 128) ? W1rel  : W2rel;
        const float* Wroot = (wb < 128) ? W1root : W2root;
        ushort* Wt = (wb < 128) ? Wt1 : Wt2;
        int idx = (wb & 127) * 256 + t;    // 128*256 total
        int n = idx >> 8, k = idx & 255;
        float v = (k < 128) ? Wrel[(size_t)k * D + n] : Wroot[(size_t)(k - 128) * D + n];
        Wt[idx] = f2b(v);
    } else {
        int cb = b - nConvBlocks - 256;
        if (cb >= nCountBlocks) return;
        for (int i = t; i < NB; i += 256) h[i] = 0;
        __syncthreads();
        int base = cb * EPB_A;
        #pragma unroll
        for (int i = 0; i < 8; ++i) {
            int e = base + i * 256 + t;
            if (e < nedges) atomicAdd(&h[dst[e] >> 8], 1);
        }
        __syncthreads();
        for (int i = t; i < NB; i += 256) if (h[i]) atomicAdd(&bcnt[i], h[i]);
    }
}

// ================= bucketed CSR build =================

__global__ __launch_bounds__(512) void bucket_scan_kernel(
    const int* __restrict__ bcnt, int* __restrict__ bbase, int* __restrict__ bcur)
{
    __shared__ int sh[NB];
    int t = threadIdx.x;
    int v = bcnt[t];
    sh[t] = v; __syncthreads();
    int val = v;
    for (int off = 1; off < NB; off <<= 1) {
        int u = (t >= off) ? sh[t - off] : 0;
        __syncthreads();
        val += u; sh[t] = val; __syncthreads();
    }
    int excl = val - v;
    bbase[t] = excl;
    bcur[t] = excl;
}

__global__ __launch_bounds__(256) void bucket_scatter_kernel(
    const int* __restrict__ src, const int* __restrict__ dst,
    int* __restrict__ bcur, uint* __restrict__ ebuf, int nedges)
{
    __shared__ int h[NB];
    __shared__ int res[NB];
    int t = threadIdx.x;
    for (int i = t; i < NB; i += 256) h[i] = 0;
    __syncthreads();
    int base = blockIdx.x * EPB_A;
    int d[8], s[8], bkt[8];
    #pragma unroll
    for (int i = 0; i < 8; ++i) {
        int e = base + i * 256 + t;
        if (e < nedges) {
            d[i] = dst[e]; s[i] = src[e]; bkt[i] = d[i] >> 8;
            atomicAdd(&h[bkt[i]], 1);
        } else bkt[i] = -1;
    }
    __syncthreads();
    for (int i = t; i < NB; i += 256) {
        int c = h[i];
        res[i] = c ? atomicAdd(&bcur[i], c) : 0;
    }
    __syncthreads();
    #pragma unroll
    for (int i = 0; i < 8; ++i) {
        if (bkt[i] >= 0) {
            int pos = atomicAdd(&res[bkt[i]], 1);
            ebuf[pos] = ((uint)(d[i] & (NPB - 1)) << 17) | (uint)s[i];
        }
    }
}

__global__ __launch_bounds__(256) void csr_finalize_kernel(
    const uint* __restrict__ ebuf, const int* __restrict__ bbase,
    const int* __restrict__ bcnt, int* __restrict__ csr_src,
    int* __restrict__ ends, int n)
{
    __shared__ int cnt[NPB];
    __shared__ int cur[NPB];
    __shared__ int sh[NPB];
    int b = blockIdx.x, t = threadIdx.x;
    int ebase = bbase[b];
    int ecnt = bcnt[b];
    cnt[t] = 0;
    __syncthreads();
    for (int i = t; i < ecnt; i += 256)
        atomicAdd(&cnt[ebuf[ebase + i] >> 17], 1);
    __syncthreads();
    int v = cnt[t];
    sh[t] = v; __syncthreads();
    int val = v;
    for (int off = 1; off < 256; off <<= 1) {
        int u = (t >= off) ? sh[t - off] : 0;
        __syncthreads();
        val += u; sh[t] = val; __syncthreads();
    }
    int node = b * NPB + t;
    if (node < n) ends[node] = ebase + val;
    cur[t] = ebase + (val - v);
    __syncthreads();
    for (int i = t; i < ecnt; i += 256) {
        uint p = ebuf[ebase + i];
        int pos = atomicAdd(&cur[p >> 17], 1);
        csr_src[pos] = (int)(p & 0x1FFFFu);
    }
}

// ================= fused layer: work-stealing gather + MFMA =================
// out = maybe_relu([gather(feat) | feat] @ Wt^T + bias)
// 256 thr = 4 waves; block = 64 consecutive nodes x 128 cols.
// Gather: 16-lane groups CLAIM nodes via LDS counter (load-balanced),
// unroll-8 load batch into one shared accumulator set (8 loads in flight/lane).
// B fragments preloaded into regs before the gather (VGPR budget 128 @ 4 w/EU).
__global__ __launch_bounds__(256, 4) void layer_fused_kernel(
    const ushort* __restrict__ feat, const int* __restrict__ csr_src,
    const int* __restrict__ ends, const ushort* __restrict__ Wt,
    const float* __restrict__ bias, float* outf, ushort* outb,
    int n, int mode)
{
    __shared__ ushort As[GBM * APAD];
    __shared__ int ctr;
    const int t = threadIdx.x;
    const int wave = t >> 6, lane = t & 63;
    const int base = blockIdx.x * GBM;
    const int l15 = lane & 15;
    const int bcol0 = wave * 32;

    if (t == 0) ctr = 0;

    // stage root half (cols 128..255): 64 rows x 16 chunks of 16B
    #pragma unroll
    for (int m = 0; m < 4; ++m) {
        int q = t + m * 256;
        int r = q >> 4, c = q & 15;
        int row = base + r;
        uint4 v = make_uint4(0, 0, 0, 0);
        if (row < n) v = reinterpret_cast<const uint4*>(feat + (size_t)row * D)[c];
        *reinterpret_cast<uint4*>(&As[r * APAD + 128 + c * 8]) = v;
    }

    // preload B fragments (L2-hot Wt) so MFMA phase has no exposed latency
    bf16x8 Bfrag[2][8];
    #pragma unroll
    for (int ks = 0; ks < 8; ++ks) {
        const int kk = ks * 32 + (lane >> 4) * 8;
        Bfrag[0][ks] = *reinterpret_cast<const bf16x8*>(Wt + (size_t)(bcol0 + l15) * 256 + kk);
        Bfrag[1][ks] = *reinterpret_cast<const bf16x8*>(Wt + (size_t)(bcol0 + 16 + l15) * 256 + kk);
    }

    __syncthreads();   // ctr visible; As gather-half writes follow

    // ---- work-stealing gather (cols 0..127) ----
    {
        const int l = t & 15;
        for (;;) {
            int my;
            if (l == 0) my = atomicAdd(&ctr, 1);
            my = __shfl(my, lane & 48, 64);
            if (my >= GBM) break;
            int node = base + my;
            float a0=0,a1=0,a2=0,a3=0,a4=0,a5=0,a6=0,a7=0;
            if (node < n) {
                int jb = (node == 0) ? 0 : ends[node - 1];
                int je = ends[node];
                int j = jb;
                for (; j + 8 <= je; j += 8) {
                    int s0 = csr_src[j + 0], s1 = csr_src[j + 1];
                    int s2 = csr_src[j + 2], s3 = csr_src[j + 3];
                    int s4 = csr_src[j + 4], s5 = csr_src[j + 5];
                    int s6 = csr_src[j + 6], s7 = csr_src[j + 7];
                    uint4 v0 = reinterpret_cast<const uint4*>(feat + (size_t)s0 * D)[l];
                    uint4 v1 = reinterpret_cast<const uint4*>(feat + (size_t)s1 * D)[l];
                    uint4 v2 = reinterpret_cast<const uint4*>(feat + (size_t)s2 * D)[l];
                    uint4 v3 = reinterpret_cast<const uint4*>(feat + (size_t)s3 * D)[l];
                    uint4 v4 = reinterpret_cast<const uint4*>(feat + (size_t)s4 * D)[l];
                    uint4 v5 = reinterpret_cast<const uint4*>(feat + (size_t)s5 * D)[l];
                    uint4 v6 = reinterpret_cast<const uint4*>(feat + (size_t)s6 * D)[l];
                    uint4 v7 = reinterpret_cast<const uint4*>(feat + (size_t)s7 * D)[l];
                    a0 += blo(v0.x); a1 += bhi(v0.x); a2 += blo(v0.y); a3 += bhi(v0.y);
                    a4 += blo(v0.z); a5 += bhi(v0.z); a6 += blo(v0.w); a7 += bhi(v0.w);
                    a0 += blo(v1.x); a1 += bhi(v1.x); a2 += blo(v1.y); a3 += bhi(v1.y);
                    a4 += blo(v1.z); a5 += bhi(v1.z); a6 += blo(v1.w); a7 += bhi(v1.w);
                    a0 += blo(v2.x); a1 += bhi(v2.x); a2 += blo(v2.y); a3 += bhi(v2.y);
                    a4 += blo(v2.z); a5 += bhi(v2.z); a6 += blo(v2.w); a7 += bhi(v2.w);
                    a0 += blo(v3.x); a1 += bhi(v3.x); a2 += blo(v3.y); a3 += bhi(v3.y);
                    a4 += blo(v3.z); a5 += bhi(v3.z); a6 += blo(v3.w); a7 += bhi(v3.w);
                    a0 += blo(v4.x); a1 += bhi(v4.x); a2 += blo(v4.y); a3 += bhi(v4.y);
                    a4 += blo(v4.z); a5 += bhi(v4.z); a6 += blo(v4.w); a7 += bhi(v4.w);
                    a0 += blo(v5.x); a1 += bhi(v5.x); a2 += blo(v5.y); a3 += bhi(v5.y);
                    a4 += blo(v5.z); a5 += bhi(v5.z); a6 += blo(v5.w); a7 += bhi(v5.w);
                    a0 += blo(v6.x); a1 += bhi(v6.x); a2 += blo(v6.y); a3 += bhi(v6.y);
                    a4 += blo(v6.z); a5 += bhi(v6.z); a6 += blo(v6.w); a7 += bhi(v6.w);
                    a0 += blo(v7.x); a1 += bhi(v7.x); a2 += blo(v7.y); a3 += bhi(v7.y);
                    a4 += blo(v7.z); a5 += bhi(v7.z); a6 += blo(v7.w); a7 += bhi(v7.w);
                }
                for (; j < je; ++j) {
                    int s0 = csr_src[j];
                    uint4 v0 = reinterpret_cast<const uint4*>(feat + (size_t)s0 * D)[l];
                    a0 += blo(v0.x); a1 += bhi(v0.x); a2 += blo(v0.y); a3 += bhi(v0.y);
                    a4 += blo(v0.z); a5 += bhi(v0.z); a6 += blo(v0.w); a7 += bhi(v0.w);
                }
            }
            uint4 rp;
            rp.x = f2b(a0) | ((uint)f2b(a1) << 16);
            rp.y = f2b(a2) | ((uint)f2b(a3) << 16);
            rp.z = f2b(a4) | ((uint)f2b(a5) << 16);
            rp.w = f2b(a6) | ((uint)f2b(a7) << 16);
            *reinterpret_cast<uint4*>(&As[my * APAD + l * 8]) = rp;
        }
    }
    __syncthreads();

    // ---- MFMA: wave covers 64 rows x 32 cols, K=256 ----
    f32x4 acc[4][2];
    #pragma unroll
    for (int rt = 0; rt < 4; ++rt)
        #pragma unroll
        for (int nt = 0; nt < 2; ++nt) acc[rt][nt] = (f32x4){0.f, 0.f, 0.f, 0.f};

    #pragma unroll 1
    for (int ks = 0; ks < 8; ++ks) {
        const int kk = ks * 32 + (lane >> 4) * 8;
        bf16x8 a0_ = *reinterpret_cast<const bf16x8*>(&As[(l15 +  0) * APAD + kk]);
        bf16x8 a1_ = *reinterpret_cast<const bf16x8*>(&As[(l15 + 16) * APAD + kk]);
        bf16x8 a2_ = *reinterpret_cast<const bf16x8*>(&As[(l15 + 32) * APAD + kk]);
        bf16x8 a3_ = *reinterpret_cast<const bf16x8*>(&As[(l15 + 48) * APAD + kk]);
        acc[0][0] = __builtin_amdgcn_mfma_f32_16x16x32_bf16(a0_, Bfrag[0][ks], acc[0][0], 0, 0, 0);
        acc[0][1] = __builtin_amdgcn_mfma_f32_16x16x32_bf16(a0_, Bfrag[1][ks], acc[0][1], 0, 0, 0);
        acc[1][0] = __builtin_amdgcn_mfma_f32_16x16x32_bf16(a1_, Bfrag[0][ks], acc[1][0], 0, 0, 0);
        acc[1][1] = __builtin_amdgcn_mfma_f32_16x16x32_bf16(a1_, Bfrag[1][ks], acc[1][1], 0, 0, 0);
        acc[2][0] = __builtin_amdgcn_mfma_f32_16x16x32_bf16(a2_, Bfrag[0][ks], acc[2][0], 0, 0, 0);
        acc[2][1] = __builtin_amdgcn_mfma_f32_16x16x32_bf16(a2_, Bfrag[1][ks], acc[2][1], 0, 0, 0);
        acc[3][0] = __builtin_amdgcn_mfma_f32_16x16x32_bf16(a3_, Bfrag[0][ks], acc[3][0], 0, 0, 0);
        acc[3][1] = __builtin_amdgcn_mfma_f32_16x16x32_bf16(a3_, Bfrag[1][ks], acc[3][1], 0, 0, 0);
    }

    // epilogue: C layout col = lane&15, row = (lane>>4)*4 + reg
    #pragma unroll
    for (int rt = 0; rt < 4; ++rt)
        #pragma unroll
        for (int nt = 0; nt < 2; ++nt) {
            int col = bcol0 + nt * 16 + l15;
            float bv = bias[col];
            #pragma unroll
            for (int r = 0; r < 4; ++r) {
                int row = base + rt * 16 + (lane >> 4) * 4 + r;
                if (row >= n) continue;
                float v = acc[rt][nt][r] + bv;
                if (mode == 0) {
                    v = fmaxf(v, 0.f);
                    outb[(size_t)row * D + col] = f2b(v);
                } else {
                    outf[(size_t)row * D + col] = v;
                }
            }
        }
}

// ================= fp32 fallback (small ws) =================

__global__ __launch_bounds__(256) void scatter_add_kernel(
    const float* __restrict__ feat, const int* __restrict__ src,
    const int* __restrict__ dst, float* agg, int nedges)
{
    int tid = blockIdx.x * 256 + threadIdx.x;
    int e = tid >> 5;
    if (e >= nedges) return;
    int l = tid & 31;
    int s = src[e];
    int d = dst[e];
    const float4 v = *reinterpret_cast<const float4*>(feat + (size_t)s * D + l * 4);
    float* o = agg + (size_t)d * D + l * 4;
    unsafeAtomicAdd(o + 0, v.x);
    unsafeAtomicAdd(o + 1, v.y);
    unsafeAtomicAdd(o + 2, v.z);
    unsafeAtomicAdd(o + 3, v.w);
}

__global__ __launch_bounds__(256) void gemm_fused_kernel(
    const float* __restrict__ A1, const float* A2,
    const float* __restrict__ Wrel, const float* __restrict__ Wroot,
    const float* __restrict__ bias, float* out, int n, int do_relu)
{
    __shared__ float Asf[TILE_R * LDS_STRIDE];
    const int t = threadIdx.x;
    const int base = blockIdx.x * TILE_R;

    #pragma unroll
    for (int m = 0; m < 8; ++m) {
        int q = t + m * 256;
        int r = q >> 6;
        int kk = (q & 63) << 2;
        int row = base + r;
        float4 v = make_float4(0.f, 0.f, 0.f, 0.f);
        if (row < n) {
            const float* p = (kk < 128) ? (A1 + (size_t)row * D + kk)
                                        : (A2 + (size_t)row * D + (kk - 128));
            v = *reinterpret_cast<const float4*>(p);
        }
        *reinterpret_cast<float4*>(&Asf[r * LDS_STRIDE + kk]) = v;
    }
    __syncthreads();

    const int rg = t >> 5;
    const int c0 = (t & 31) << 2;

    float acc[4][4];
    #pragma unroll
    for (int i = 0; i < 4; ++i)
        #pragma unroll
        for (int j = 0; j < 4; ++j) acc[i][j] = 0.f;

    const float* Wmats[2] = {Wrel, Wroot};
    #pragma unroll
    for (int half = 0; half < 2; ++half) {
        const float* W = Wmats[half];
        const int kb = half * 128;
        for (int k = 0; k < 128; k += 4) {
            float w[4][4];
            #pragma unroll
            for (int kk = 0; kk < 4; ++kk) {
                float4 wv = *reinterpret_cast<const float4*>(W + (size_t)(k + kk) * D + c0);
                w[kk][0] = wv.x; w[kk][1] = wv.y; w[kk][2] = wv.z; w[kk][3] = wv.w;
            }
            #pragma unroll
            for (int i = 0; i < 4; ++i) {
                float4 av = *reinterpret_cast<const float4*>(&Asf[(rg * 4 + i) * LDS_STRIDE + kb + k]);
                float a[4] = {av.x, av.y, av.z, av.w};
                #pragma unroll
                for (int kk = 0; kk < 4; ++kk)
                    #pragma unroll
                    for (int j = 0; j < 4; ++j)
                        acc[i][j] = fmaf(a[kk], w[kk][j], acc[i][j]);
            }
        }
    }

    float4 bv = *reinterpret_cast<const float4*>(bias + c0);
    float b[4] = {bv.x, bv.y, bv.z, bv.w};
    #pragma unroll
    for (int i = 0; i < 4; ++i) {
        int row = base + rg * 4 + i;
        if (row >= n) continue;
        float o[4];
        #pragma unroll
        for (int j = 0; j < 4; ++j) {
            float v = acc[i][j] + b[j];
            if (do_relu) v = fmaxf(v, 0.f);
            o[j] = v;
        }
        *reinterpret_cast<float4*>(out + (size_t)row * D + c0) =
            make_float4(o[0], o[1], o[2], o[3]);
    }
}

extern "C" void kernel_launch(void* const* d_in, const int* in_sizes, int n_in,
                              void* d_out, int out_size, void* d_ws, size_t ws_size,
                              hipStream_t stream) {
    const float* x       = (const float*)d_in[0];
    const int*   ei      = (const int*)d_in[1];
    const float* W1_rel  = (const float*)d_in[2];
    const float* b1      = (const float*)d_in[3];
    const float* W1_root = (const float*)d_in[4];
    const float* W2_rel  = (const float*)d_in[5];
    const float* b2      = (const float*)d_in[6];
    const float* W2_root = (const float*)d_in[7];
    float* out = (float*)d_out;

    const int E = in_sizes[1] / 2;
    const int N = in_sizes[0] / D;
    const int* src = ei;
    const int* dst = ei + E;

    // ws layout. ebuf aliases hb (dead until layer-1 output).
    size_t hbB   = ((size_t)N * D * 2 + 255) & ~(size_t)255;       // >= E*4 needed too
    size_t xbB   = ((size_t)N * D * 2 + 255) & ~(size_t)255;
    size_t csrB  = ((size_t)E * 4 + 255) & ~(size_t)255;
    size_t endB  = ((size_t)(N + 1) * 4 + 255) & ~(size_t)255;
    size_t bktB  = ((size_t)(3 * NB + 8) * 4 + 255) & ~(size_t)255;
    size_t wtB   = (size_t)128 * 256 * 2;
    size_t need = hbB + xbB + csrB + endB + bktB + 2 * wtB;

    bool pack_ok = (N <= 131072) && ((size_t)E * 4 <= hbB);

    if (ws_size >= need && pack_ok) {
        char* w = (char*)d_ws;
        ushort* hb      = (ushort*)w;            w += hbB;
        ushort* xb      = (ushort*)w;            w += xbB;
        int*    csr_src = (int*)w;               w += csrB;
        int*    ends    = (int*)w;               w += endB;
        int*    bcnt    = (int*)w;
        int*    bbase   = bcnt + NB;
        int*    bcur    = bbase + NB;            w += bktB;
        ushort* Wt1     = (ushort*)w;            w += wtB;
        ushort* Wt2     = (ushort*)w;
        uint*   ebuf    = (uint*)hb;             // alias: dead before layer 1 output

        const int aBlocks = (E + EPB_A - 1) / EPB_A;
        const int nbu = (N + NPB - 1) / NPB;
        const int n8 = N * D / 8;
        const int nConvBlocks = (n8 + 255) / 256;

        // prep (conv + Wt1 + Wt2 + bucket_count) after zeroing bcnt
        hipMemsetAsync(bcnt, 0, NB * sizeof(int), stream);
        prep_kernel<<<nConvBlocks + 256 + aBlocks, 256, 0, stream>>>(
            x, xb, n8, W1_rel, W1_root, Wt1, W2_rel, W2_root, Wt2,
            dst, bcnt, E, nConvBlocks, aBlocks);

        bucket_scan_kernel<<<1, NB, 0, stream>>>(bcnt, bbase, bcur);
        bucket_scatter_kernel<<<aBlocks, 256, 0, stream>>>(src, dst, bcur, ebuf, E);
        csr_finalize_kernel<<<nbu, 256, 0, stream>>>(ebuf, bbase, bcnt, csr_src, ends, N);

        int layerBlocks = (N + GBM - 1) / GBM;

        // layer 1: xb -> hb (bf16, relu)
        layer_fused_kernel<<<layerBlocks, 256, 0, stream>>>(
            xb, csr_src, ends, Wt1, b1, nullptr, hb, N, 0);
        // layer 2: hb -> out (fp32)
        layer_fused_kernel<<<layerBlocks, 256, 0, stream>>>(
            hb, csr_src, ends, Wt2, b2, out, nullptr, N, 1);
    } else {
        // fallback: fp32 atomic scatter + vector gemm
        float* agg = (float*)d_ws;
        size_t aggBytes = (size_t)N * D * sizeof(float);
        int scatterBlocks = (E * 32 + 255) / 256;
        int gemmBlocks = (N + TILE_R - 1) / TILE_R;
        hipMemsetAsync(agg, 0, aggBytes, stream);
        scatter_add_kernel<<<scatterBlocks, 256, 0, stream>>>(x, src, dst, agg, E);
        gemm_fused_kernel<<<gemmBlocks, 256, 0, stream>>>(agg, x, W1_rel, W1_root, b1, out, N, 1);
        hipMemsetAsync(agg, 0, aggBytes, stream);
        scatter_add_kernel<<<scatterBlocks, 256, 0, stream>>>(out, src, dst, agg, E);
        gemm_fused_kernel<<<gemmBlocks, 256, 0, stream>>>(agg, out, W2_rel, W2_root, b2, out, N, 0);
    }
}

// Round 9
// 261.889 us; speedup vs baseline: 1.2043x; 1.2043x over previous
//
#include <hip/hip_runtime.h>

#define D 128
#define TILE_R 32
#define LDS_STRIDE 260
#define GBM 64            // rows (nodes) per fused-layer block

#define NB 512            // coarse buckets
#define NPB 256           // nodes per bucket (dst >> 8)
#define EPB_A 2048        // edges per block in stage A

typedef __attribute__((ext_vector_type(8))) short bf16x8;
typedef __attribute__((ext_vector_type(4))) float f32x4;

static __device__ __forceinline__ ushort f2b(float f) {
    union { float f; uint u; } v; v.f = f;
    uint r = (v.u + 0x7FFFu + ((v.u >> 16) & 1u)) >> 16;   // RNE
    return (ushort)r;
}
static __device__ __forceinline__ float blo(uint u) {
    union { uint u; float f; } v; v.u = u << 16; return v.f;
}
static __device__ __forceinline__ float bhi(uint u) {
    union { uint u; float f; } v; v.u = u & 0xFFFF0000u; return v.f;
}
// LDS A-tile: row r = 256 bf16 = 32 chunks of 16B; chunk q stored at q^(r&7).
// 2-way bank alias on reads (rows +8) = free; tile is exactly 32KB -> 5 blocks/CU.
static __device__ __forceinline__ int swz(int r, int q) {
    return r * 256 + ((q ^ (r & 7)) << 3);   // ushort index
}

// ================= prep: conv(x->bf16) + Wt1 + Wt2 + bucket_count, one kernel =================
__global__ __launch_bounds__(256) void prep_kernel(
    const float* __restrict__ x, ushort* __restrict__ xb, int n8,
    const float* __restrict__ W1rel, const float* __restrict__ W1root, ushort* __restrict__ Wt1,
    const float* __restrict__ W2rel, const float* __restrict__ W2root, ushort* __restrict__ Wt2,
    const int* __restrict__ dst, int* __restrict__ bcnt, int nedges,
    int nConvBlocks, int nCountBlocks)
{
    __shared__ int h[NB];
    const int b = blockIdx.x, t = threadIdx.x;

    if (b < nConvBlocks) {
        int i = b * 256 + t;
        if (i >= n8) return;
        float4 a = reinterpret_cast<const float4*>(x)[i * 2];
        float4 c = reinterpret_cast<const float4*>(x)[i * 2 + 1];
        uint4 r;
        r.x = f2b(a.x) | ((uint)f2b(a.y) << 16);
        r.y = f2b(a.z) | ((uint)f2b(a.w) << 16);
        r.z = f2b(c.x) | ((uint)f2b(c.y) << 16);
        r.w = f2b(c.z) | ((uint)f2b(c.w) << 16);
        reinterpret_cast<uint4*>(xb)[i] = r;
    } else if (b < nConvBlocks + 256) {
        int wb = b - nConvBlocks;          // 0..255 ; 0..127 -> Wt1, 128..255 -> Wt2
        const float* Wrel  = (wb < 128) ? W1rel  : W2rel;
        const float* Wroot = (wb < 128) ? W1root : W2root;
        ushort* Wt = (wb < 128) ? Wt1 : Wt2;
        int idx = (wb & 127) * 256 + t;    // 128*256 total
        int n = idx >> 8, k = idx & 255;
        float v = (k < 128) ? Wrel[(size_t)k * D + n] : Wroot[(size_t)(k - 128) * D + n];
        Wt[idx] = f2b(v);
    } else {
        int cb = b - nConvBlocks - 256;
        if (cb >= nCountBlocks) return;
        for (int i = t; i < NB; i += 256) h[i] = 0;
        __syncthreads();
        int base = cb * EPB_A;
        #pragma unroll
        for (int i = 0; i < 8; ++i) {
            int e = base + i * 256 + t;
            if (e < nedges) atomicAdd(&h[dst[e] >> 8], 1);
        }
        __syncthreads();
        for (int i = t; i < NB; i += 256) if (h[i]) atomicAdd(&bcnt[i], h[i]);
    }
}

// ================= bucketed CSR build =================

__global__ __launch_bounds__(512) void bucket_scan_kernel(
    const int* __restrict__ bcnt, int* __restrict__ bbase, int* __restrict__ bcur)
{
    __shared__ int sh[NB];
    int t = threadIdx.x;
    int v = bcnt[t];
    sh[t] = v; __syncthreads();
    int val = v;
    for (int off = 1; off < NB; off <<= 1) {
        int u = (t >= off) ? sh[t - off] : 0;
        __syncthreads();
        val += u; sh[t] = val; __syncthreads();
    }
    int excl = val - v;
    bbase[t] = excl;
    bcur[t] = excl;
}

__global__ __launch_bounds__(256) void bucket_scatter_kernel(
    const int* __restrict__ src, const int* __restrict__ dst,
    int* __restrict__ bcur, uint* __restrict__ ebuf, int nedges)
{
    __shared__ int h[NB];
    __shared__ int res[NB];
    int t = threadIdx.x;
    for (int i = t; i < NB; i += 256) h[i] = 0;
    __syncthreads();
    int base = blockIdx.x * EPB_A;
    int d[8], s[8], bkt[8];
    #pragma unroll
    for (int i = 0; i < 8; ++i) {
        int e = base + i * 256 + t;
        if (e < nedges) {
            d[i] = dst[e]; s[i] = src[e]; bkt[i] = d[i] >> 8;
            atomicAdd(&h[bkt[i]], 1);
        } else bkt[i] = -1;
    }
    __syncthreads();
    for (int i = t; i < NB; i += 256) {
        int c = h[i];
        res[i] = c ? atomicAdd(&bcur[i], c) : 0;
    }
    __syncthreads();
    #pragma unroll
    for (int i = 0; i < 8; ++i) {
        if (bkt[i] >= 0) {
            int pos = atomicAdd(&res[bkt[i]], 1);
            ebuf[pos] = ((uint)(d[i] & (NPB - 1)) << 17) | (uint)s[i];
        }
    }
}

__global__ __launch_bounds__(256) void csr_finalize_kernel(
    const uint* __restrict__ ebuf, const int* __restrict__ bbase,
    const int* __restrict__ bcnt, int* __restrict__ csr_src,
    int* __restrict__ ends, int n)
{
    __shared__ int cnt[NPB];
    __shared__ int cur[NPB];
    __shared__ int sh[NPB];
    int b = blockIdx.x, t = threadIdx.x;
    int ebase = bbase[b];
    int ecnt = bcnt[b];
    cnt[t] = 0;
    __syncthreads();
    for (int i = t; i < ecnt; i += 256)
        atomicAdd(&cnt[ebuf[ebase + i] >> 17], 1);
    __syncthreads();
    int v = cnt[t];
    sh[t] = v; __syncthreads();
    int val = v;
    for (int off = 1; off < 256; off <<= 1) {
        int u = (t >= off) ? sh[t - off] : 0;
        __syncthreads();
        val += u; sh[t] = val; __syncthreads();
    }
    int node = b * NPB + t;
    if (node < n) ends[node] = ebase + val;
    cur[t] = ebase + (val - v);
    __syncthreads();
    for (int i = t; i < ecnt; i += 256) {
        uint p = ebuf[ebase + i];
        int pos = atomicAdd(&cur[p >> 17], 1);
        csr_src[pos] = (int)(p & 0x1FFFFu);
    }
}

// ================= fused layer (R7 structure + 32KB swizzled LDS) =================
// out = maybe_relu([gather(feat) | feat] @ Wt^T + bias)
// 256 thr = 4 waves; block = 64 consecutive nodes x 128 cols.
// A-tile exactly 32KB (XOR chunk swizzle, no pad) -> 5 blocks/CU.
// Gather: static 4 nodes per 16-lane group, unroll-4. B-frags re-read from
// L2-hot Wt inside the ks loop (keeps VGPR ~52, no spill).
__global__ __launch_bounds__(256, 4) void layer_fused_kernel(
    const ushort* __restrict__ feat, const int* __restrict__ csr_src,
    const int* __restrict__ ends, const ushort* __restrict__ Wt,
    const float* __restrict__ bias, float* outf, ushort* outb,
    int n, int mode)
{
    __shared__ ushort As[GBM * 256];   // 32768 B exactly
    const int t = threadIdx.x;
    const int wave = t >> 6, lane = t & 63;
    const int base = blockIdx.x * GBM;
    const int l15 = lane & 15;

    // stage root half (chunks 16..31): 64 rows x 16 chunks of 16B
    #pragma unroll
    for (int m = 0; m < 4; ++m) {
        int q = t + m * 256;
        int r = q >> 4, c = q & 15;
        int row = base + r;
        uint4 v = make_uint4(0, 0, 0, 0);
        if (row < n) v = reinterpret_cast<const uint4*>(feat + (size_t)row * D)[c];
        *reinterpret_cast<uint4*>(&As[swz(r, 16 + c)]) = v;
    }

    // gather half (chunks 0..15): group g (16 lanes) handles rows g*4..g*4+3
    {
        const int g = t >> 4, l = t & 15;
        #pragma unroll 1
        for (int sub = 0; sub < 4; ++sub) {
            int r = g * 4 + sub;
            int node = base + r;
            float a0=0,a1=0,a2=0,a3=0,a4=0,a5=0,a6=0,a7=0;
            float c0=0,c1=0,c2=0,c3=0,c4=0,c5=0,c6=0,c7=0;
            float e0=0,e1=0,e2=0,e3=0,e4=0,e5=0,e6=0,e7=0;
            float g0=0,g1=0,g2=0,g3=0,g4=0,g5=0,g6=0,g7=0;
            if (node < n) {
                int jb = (node == 0) ? 0 : ends[node - 1];
                int je = ends[node];
                int j = jb;
                for (; j + 4 <= je; j += 4) {
                    int s0 = csr_src[j], s1 = csr_src[j + 1];
                    int s2 = csr_src[j + 2], s3 = csr_src[j + 3];
                    uint4 v0 = reinterpret_cast<const uint4*>(feat + (size_t)s0 * D)[l];
                    uint4 v1 = reinterpret_cast<const uint4*>(feat + (size_t)s1 * D)[l];
                    uint4 v2 = reinterpret_cast<const uint4*>(feat + (size_t)s2 * D)[l];
                    uint4 v3 = reinterpret_cast<const uint4*>(feat + (size_t)s3 * D)[l];
                    a0 += blo(v0.x); a1 += bhi(v0.x); a2 += blo(v0.y); a3 += bhi(v0.y);
                    a4 += blo(v0.z); a5 += bhi(v0.z); a6 += blo(v0.w); a7 += bhi(v0.w);
                    c0 += blo(v1.x); c1 += bhi(v1.x); c2 += blo(v1.y); c3 += bhi(v1.y);
                    c4 += blo(v1.z); c5 += bhi(v1.z); c6 += blo(v1.w); c7 += bhi(v1.w);
                    e0 += blo(v2.x); e1 += bhi(v2.x); e2 += blo(v2.y); e3 += bhi(v2.y);
                    e4 += blo(v2.z); e5 += bhi(v2.z); e6 += blo(v2.w); e7 += bhi(v2.w);
                    g0 += blo(v3.x); g1 += bhi(v3.x); g2 += blo(v3.y); g3 += bhi(v3.y);
                    g4 += blo(v3.z); g5 += bhi(v3.z); g6 += blo(v3.w); g7 += bhi(v3.w);
                }
                for (; j < je; ++j) {
                    int s0 = csr_src[j];
                    uint4 v0 = reinterpret_cast<const uint4*>(feat + (size_t)s0 * D)[l];
                    a0 += blo(v0.x); a1 += bhi(v0.x); a2 += blo(v0.y); a3 += bhi(v0.y);
                    a4 += blo(v0.z); a5 += bhi(v0.z); a6 += blo(v0.w); a7 += bhi(v0.w);
                }
            }
            uint4 rp;
            rp.x = f2b(a0 + c0 + e0 + g0) | ((uint)f2b(a1 + c1 + e1 + g1) << 16);
            rp.y = f2b(a2 + c2 + e2 + g2) | ((uint)f2b(a3 + c3 + e3 + g3) << 16);
            rp.z = f2b(a4 + c4 + e4 + g4) | ((uint)f2b(a5 + c5 + e5 + g5) << 16);
            rp.w = f2b(a6 + c6 + e6 + g6) | ((uint)f2b(a7 + c7 + e7 + g7) << 16);
            *reinterpret_cast<uint4*>(&As[swz(r, l)]) = rp;
        }
    }
    __syncthreads();

    // MFMA: wave covers 64 rows x 32 cols, K=256
    const int bcol0 = wave * 32;
    f32x4 acc[4][2];
    #pragma unroll
    for (int rt = 0; rt < 4; ++rt)
        #pragma unroll
        for (int nt = 0; nt < 2; ++nt) acc[rt][nt] = (f32x4){0.f, 0.f, 0.f, 0.f};

    #pragma unroll 1
    for (int ks = 0; ks < 8; ++ks) {
        const int kk = ks * 32 + (lane >> 4) * 8;        // ushort offset within row
        const int ch = ks * 4 + (lane >> 4);             // 16B chunk index
        bf16x8 a0_ = *reinterpret_cast<const bf16x8*>(&As[swz(l15 +  0, ch)]);
        bf16x8 a1_ = *reinterpret_cast<const bf16x8*>(&As[swz(l15 + 16, ch)]);
        bf16x8 a2_ = *reinterpret_cast<const bf16x8*>(&As[swz(l15 + 32, ch)]);
        bf16x8 a3_ = *reinterpret_cast<const bf16x8*>(&As[swz(l15 + 48, ch)]);
        bf16x8 b0_ = *reinterpret_cast<const bf16x8*>(Wt + (size_t)(bcol0 + l15) * 256 + kk);
        bf16x8 b1_ = *reinterpret_cast<const bf16x8*>(Wt + (size_t)(bcol0 + 16 + l15) * 256 + kk);
        acc[0][0] = __builtin_amdgcn_mfma_f32_16x16x32_bf16(a0_, b0_, acc[0][0], 0, 0, 0);
        acc[0][1] = __builtin_amdgcn_mfma_f32_16x16x32_bf16(a0_, b1_, acc[0][1], 0, 0, 0);
        acc[1][0] = __builtin_amdgcn_mfma_f32_16x16x32_bf16(a1_, b0_, acc[1][0], 0, 0, 0);
        acc[1][1] = __builtin_amdgcn_mfma_f32_16x16x32_bf16(a1_, b1_, acc[1][1], 0, 0, 0);
        acc[2][0] = __builtin_amdgcn_mfma_f32_16x16x32_bf16(a2_, b0_, acc[2][0], 0, 0, 0);
        acc[2][1] = __builtin_amdgcn_mfma_f32_16x16x32_bf16(a2_, b1_, acc[2][1], 0, 0, 0);
        acc[3][0] = __builtin_amdgcn_mfma_f32_16x16x32_bf16(a3_, b0_, acc[3][0], 0, 0, 0);
        acc[3][1] = __builtin_amdgcn_mfma_f32_16x16x32_bf16(a3_, b1_, acc[3][1], 0, 0, 0);
    }

    // epilogue: C layout col = lane&15, row = (lane>>4)*4 + reg
    #pragma unroll
    for (int rt = 0; rt < 4; ++rt)
        #pragma unroll
        for (int nt = 0; nt < 2; ++nt) {
            int col = bcol0 + nt * 16 + l15;
            float bv = bias[col];
            #pragma unroll
            for (int r = 0; r < 4; ++r) {
                int row = base + rt * 16 + (lane >> 4) * 4 + r;
                if (row >= n) continue;
                float v = acc[rt][nt][r] + bv;
                if (mode == 0) {
                    v = fmaxf(v, 0.f);
                    outb[(size_t)row * D + col] = f2b(v);
                } else {
                    outf[(size_t)row * D + col] = v;
                }
            }
        }
}

// ================= fp32 fallback (small ws) =================

__global__ __launch_bounds__(256) void scatter_add_kernel(
    const float* __restrict__ feat, const int* __restrict__ src,
    const int* __restrict__ dst, float* agg, int nedges)
{
    int tid = blockIdx.x * 256 + threadIdx.x;
    int e = tid >> 5;
    if (e >= nedges) return;
    int l = tid & 31;
    int s = src[e];
    int d = dst[e];
    const float4 v = *reinterpret_cast<const float4*>(feat + (size_t)s * D + l * 4);
    float* o = agg + (size_t)d * D + l * 4;
    unsafeAtomicAdd(o + 0, v.x);
    unsafeAtomicAdd(o + 1, v.y);
    unsafeAtomicAdd(o + 2, v.z);
    unsafeAtomicAdd(o + 3, v.w);
}

__global__ __launch_bounds__(256) void gemm_fused_kernel(
    const float* __restrict__ A1, const float* A2,
    const float* __restrict__ Wrel, const float* __restrict__ Wroot,
    const float* __restrict__ bias, float* out, int n, int do_relu)
{
    __shared__ float Asf[TILE_R * LDS_STRIDE];
    const int t = threadIdx.x;
    const int base = blockIdx.x * TILE_R;

    #pragma unroll
    for (int m = 0; m < 8; ++m) {
        int q = t + m * 256;
        int r = q >> 6;
        int kk = (q & 63) << 2;
        int row = base + r;
        float4 v = make_float4(0.f, 0.f, 0.f, 0.f);
        if (row < n) {
            const float* p = (kk < 128) ? (A1 + (size_t)row * D + kk)
                                        : (A2 + (size_t)row * D + (kk - 128));
            v = *reinterpret_cast<const float4*>(p);
        }
        *reinterpret_cast<float4*>(&Asf[r * LDS_STRIDE + kk]) = v;
    }
    __syncthreads();

    const int rg = t >> 5;
    const int c0 = (t & 31) << 2;

    float acc[4][4];
    #pragma unroll
    for (int i = 0; i < 4; ++i)
        #pragma unroll
        for (int j = 0; j < 4; ++j) acc[i][j] = 0.f;

    const float* Wmats[2] = {Wrel, Wroot};
    #pragma unroll
    for (int half = 0; half < 2; ++half) {
        const float* W = Wmats[half];
        const int kb = half * 128;
        for (int k = 0; k < 128; k += 4) {
            float w[4][4];
            #pragma unroll
            for (int kk = 0; kk < 4; ++kk) {
                float4 wv = *reinterpret_cast<const float4*>(W + (size_t)(k + kk) * D + c0);
                w[kk][0] = wv.x; w[kk][1] = wv.y; w[kk][2] = wv.z; w[kk][3] = wv.w;
            }
            #pragma unroll
            for (int i = 0; i < 4; ++i) {
                float4 av = *reinterpret_cast<const float4*>(&Asf[(rg * 4 + i) * LDS_STRIDE + kb + k]);
                float a[4] = {av.x, av.y, av.z, av.w};
                #pragma unroll
                for (int kk = 0; kk < 4; ++kk)
                    #pragma unroll
                    for (int j = 0; j < 4; ++j)
                        acc[i][j] = fmaf(a[kk], w[kk][j], acc[i][j]);
            }
        }
    }

    float4 bv = *reinterpret_cast<const float4*>(bias + c0);
    float b[4] = {bv.x, bv.y, bv.z, bv.w};
    #pragma unroll
    for (int i = 0; i < 4; ++i) {
        int row = base + rg * 4 + i;
        if (row >= n) continue;
        float o[4];
        #pragma unroll
        for (int j = 0; j < 4; ++j) {
            float v = acc[i][j] + b[j];
            if (do_relu) v = fmaxf(v, 0.f);
            o[j] = v;
        }
        *reinterpret_cast<float4*>(out + (size_t)row * D + c0) =
            make_float4(o[0], o[1], o[2], o[3]);
    }
}

extern "C" void kernel_launch(void* const* d_in, const int* in_sizes, int n_in,
                              void* d_out, int out_size, void* d_ws, size_t ws_size,
                              hipStream_t stream) {
    const float* x       = (const float*)d_in[0];
    const int*   ei      = (const int*)d_in[1];
    const float* W1_rel  = (const float*)d_in[2];
    const float* b1      = (const float*)d_in[3];
    const float* W1_root = (const float*)d_in[4];
    const float* W2_rel  = (const float*)d_in[5];
    const float* b2      = (const float*)d_in[6];
    const float* W2_root = (const float*)d_in[7];
    float* out = (float*)d_out;

    const int E = in_sizes[1] / 2;
    const int N = in_sizes[0] / D;
    const int* src = ei;
    const int* dst = ei + E;

    // ws layout. ebuf aliases hb (dead until layer-1 output).
    size_t hbB   = ((size_t)N * D * 2 + 255) & ~(size_t)255;       // >= E*4 needed too
    size_t xbB   = ((size_t)N * D * 2 + 255) & ~(size_t)255;
    size_t csrB  = ((size_t)E * 4 + 255) & ~(size_t)255;
    size_t endB  = ((size_t)(N + 1) * 4 + 255) & ~(size_t)255;
    size_t bktB  = ((size_t)(3 * NB + 8) * 4 + 255) & ~(size_t)255;
    size_t wtB   = (size_t)128 * 256 * 2;
    size_t need = hbB + xbB + csrB + endB + bktB + 2 * wtB;

    bool pack_ok = (N <= 131072) && ((size_t)E * 4 <= hbB);

    if (ws_size >= need && pack_ok) {
        char* w = (char*)d_ws;
        ushort* hb      = (ushort*)w;            w += hbB;
        ushort* xb      = (ushort*)w;            w += xbB;
        int*    csr_src = (int*)w;               w += csrB;
        int*    ends    = (int*)w;               w += endB;
        int*    bcnt    = (int*)w;
        int*    bbase   = bcnt + NB;
        int*    bcur    = bbase + NB;            w += bktB;
        ushort* Wt1     = (ushort*)w;            w += wtB;
        ushort* Wt2     = (ushort*)w;
        uint*   ebuf    = (uint*)hb;             // alias: dead before layer 1 output

        const int aBlocks = (E + EPB_A - 1) / EPB_A;
        const int nbu = (N + NPB - 1) / NPB;
        const int n8 = N * D / 8;
        const int nConvBlocks = (n8 + 255) / 256;

        // prep (conv + Wt1 + Wt2 + bucket_count) after zeroing bcnt
        hipMemsetAsync(bcnt, 0, NB * sizeof(int), stream);
        prep_kernel<<<nConvBlocks + 256 + aBlocks, 256, 0, stream>>>(
            x, xb, n8, W1_rel, W1_root, Wt1, W2_rel, W2_root, Wt2,
            dst, bcnt, E, nConvBlocks, aBlocks);

        bucket_scan_kernel<<<1, NB, 0, stream>>>(bcnt, bbase, bcur);
        bucket_scatter_kernel<<<aBlocks, 256, 0, stream>>>(src, dst, bcur, ebuf, E);
        csr_finalize_kernel<<<nbu, 256, 0, stream>>>(ebuf, bbase, bcnt, csr_src, ends, N);

        int layerBlocks = (N + GBM - 1) / GBM;

        // layer 1: xb -> hb (bf16, relu)
        layer_fused_kernel<<<layerBlocks, 256, 0, stream>>>(
            xb, csr_src, ends, Wt1, b1, nullptr, hb, N, 0);
        // layer 2: hb -> out (fp32)
        layer_fused_kernel<<<layerBlocks, 256, 0, stream>>>(
            hb, csr_src, ends, Wt2, b2, out, nullptr, N, 1);
    } else {
        // fallback: fp32 atomic scatter + vector gemm
        float* agg = (float*)d_ws;
        size_t aggBytes = (size_t)N * D * sizeof(float);
        int scatterBlocks = (E * 32 + 255) / 256;
        int gemmBlocks = (N + TILE_R - 1) / TILE_R;
        hipMemsetAsync(agg, 0, aggBytes, stream);
        scatter_add_kernel<<<scatterBlocks, 256, 0, stream>>>(x, src, dst, agg, E);
        gemm_fused_kernel<<<gemmBlocks, 256, 0, stream>>>(agg, x, W1_rel, W1_root, b1, out, N, 1);
        hipMemsetAsync(agg, 0, aggBytes, stream);
        scatter_add_kernel<<<scatterBlocks, 256, 0, stream>>>(out, src, dst, agg, E);
        gemm_fused_kernel<<<gemmBlocks, 256, 0, stream>>>(agg, out, W2_rel, W2_root, b2, out, N, 0);
    }
}